// Round 3
// baseline (206.121 us; speedup 1.0000x reference)
//
#include <hip/hip_runtime.h>

// BagOfWords: input [1024, 512] int32 tokens in [0, 50257).
// Output [1024, 50256] float32: per-row histogram, vocab bin 0 dropped.
//
// R7: fill + sparse-winner design.
//   Structural fact: <=2 MB of the 205.8 MB output is nonzero (512 tokens /
//   50256 bins per row). R2 evidence: a pure streaming fill runs at ~6.7 TB/s
//   (123 us for 823 MB) EVEN WHEN the MALL absorbs all of it (two fill
//   dispatches showed ~24 KB HBM traffic at identical duration) -- that rate
//   is the store-issue ceiling, and only a do-nothing-else kernel reaches it.
//   Every fused variant (R0/R2) stalled the store pipe at ~2.9 TB/s because
//   stores share the wave with LDS phases (and VGPR reuse of store-data regs
//   forces vmcnt waits).
//
//   K1: pure grid-stride float4 zero of all 205.8 MB. Plain stores, NOT
//       nontemporal (R4: nt bypasses MALL absorption, +10 us). ~31 us.
//   K2: per-row duplicate-combine + sparse scatter of PLAIN stores (R1
//       lesson: 524K global atomic RMWs = 65 us; plain stores pipeline).
//       16 KB LDS chunk-histogram, 13 chunks of 4096 bins. Winner trick:
//       ds_add_rtn returning 0 marks the bin owner; after an LDS barrier the
//       owner reads the final count, stores ONE dword to out, and re-zeros
//       its bin (no 4096-bin scan, no 16 KB readback/re-zero per chunk).
//       ~40 winners/chunk/row; 2 MB of stores total. ~3-6 us.
//
//   Kernel boundary = release(K1 dirty zeros -> MALL) + acquire(K2), so K2's
//   scattered stores merge into zeroed lines. No fused-barrier coherence
//   hazard across XCDs.

#define BATCH 1024
#define SEQ 512
#define VOCAB 50257
#define OUT_COLS (VOCAB - 1)                    // 50256
#define OUT_FLOATS ((size_t)BATCH * OUT_COLS)   // 51,462,144
#define OUT_F4 (OUT_FLOATS / 4)                 // 12,865,536
#define CHUNK 4096
#define NCHUNK 13
#define BLOCK 256
#define ZERO_BLOCKS 2048

// LDS-only barrier: waits ds ops (lgkmcnt) but does NOT drain global stores.
#define LDS_BAR()                                              \
    do {                                                       \
        asm volatile("s_waitcnt lgkmcnt(0)" ::: "memory");     \
        __builtin_amdgcn_s_barrier();                          \
        asm volatile("" ::: "memory");                         \
    } while (0)

__global__ __launch_bounds__(BLOCK) void bow_zero_kernel(float4* __restrict__ out) {
    size_t i = (size_t)blockIdx.x * BLOCK + threadIdx.x;
    const size_t stride = (size_t)ZERO_BLOCKS * BLOCK;
    const float4 z = make_float4(0.0f, 0.0f, 0.0f, 0.0f);
    for (; i < OUT_F4; i += stride) {
        out[i] = z;   // plain global_store_dwordx4, nothing else in the loop
    }
}

__global__ __launch_bounds__(BLOCK) void bow_sparse_kernel(
    const int* __restrict__ tokens, float* __restrict__ out) {
    __shared__ unsigned int hist[CHUNK];  // 16 KB

    const int t = threadIdx.x;
    const int b = blockIdx.x;  // one block per row

    // Zero the 4096-bin chunk histogram once.
    const uint4 z4 = make_uint4(0u, 0u, 0u, 0u);
    #pragma unroll
    for (int k = 0; k < 4; ++k)
        *(uint4*)&hist[t * 4 + k * (BLOCK * 4)] = z4;

    // This row's 512 tokens, int2 per thread, in registers for all 13 chunks.
    const int2 tk = ((const int2*)(tokens + (size_t)b * SEQ))[t];
    const unsigned int cx = (unsigned int)(tk.x - 1);  // tok==0 -> huge
    const unsigned int cy = (unsigned int)(tk.y - 1);

    float* orow = out + (size_t)b * OUT_COLS;

    LDS_BAR();  // zeros visible

    for (int c = 0; c < NCHUNK; ++c) {
        const unsigned int c0 = (unsigned int)c * CHUNK;

        // Accumulate; atomicAdd returning 0 marks this thread the bin owner.
        const unsigned int rx = cx - c0;
        const unsigned int ry = cy - c0;
        bool wx = false, wy = false;
        if (rx < CHUNK) wx = (atomicAdd(&hist[rx], 1u) == 0u);
        if (ry < CHUNK) wy = (atomicAdd(&hist[ry], 1u) == 0u);

        LDS_BAR();  // all adds for this chunk complete

        // Owners: read final count, one plain dword store, re-zero own bin.
        if (wx) {
            const unsigned int cnt = hist[rx];
            orow[c0 + rx] = (float)cnt;
            hist[rx] = 0u;
        }
        if (wy) {
            const unsigned int cnt = hist[ry];
            orow[c0 + ry] = (float)cnt;
            hist[ry] = 0u;
        }

        LDS_BAR();  // re-zeros visible before next chunk's adds
    }
}

extern "C" void kernel_launch(void* const* d_in, const int* in_sizes, int n_in,
                              void* d_out, int out_size, void* d_ws, size_t ws_size,
                              hipStream_t stream) {
    const int* tokens = (const int*)d_in[0];
    float* out = (float*)d_out;

    bow_zero_kernel<<<dim3(ZERO_BLOCKS), dim3(BLOCK), 0, stream>>>((float4*)out);
    bow_sparse_kernel<<<dim3(BATCH), dim3(BLOCK), 0, stream>>>(tokens, out);
}

// Round 5
// 194.887 us; speedup vs baseline: 1.0576x; 1.0576x over previous
//
#include <hip/hip_runtime.h>

// BagOfWords: input [1024, 512] int32 tokens in [0, 50257).
// Output [1024, 50256] float32: per-row histogram, vocab bin 0 dropped.
//
// R8 (resubmit after container-acquisition infra failure in R4; kernel was
// never measured): mask-gated streaming store (single kernel).
//
// Evidence so far:
//   - Pure streaming fill = 6.7 TB/s (123 us / 823 MB), even when the MALL
//     absorbs all writes (R2: fills with ~0 HBM traffic, same duration).
//   - Scattered dword stores to L2-cold lines = ~10 G lines/s: R1 atomics
//     (Z+A=102) vs R3 plain-store scatter (Z+S=83) differ by only 19 us ->
//     the write-allocate line-miss traffic, not the RMW, is the cost.
//     Separate-kernel sparse scatter is dead.
//   - R0/R2 fused kernels streamed at only ~2.9 TB/s because every store's
//     data came from a 16 KB LDS readback (ds_read_b128 -> cvt -> store
//     chain re-serialized per chunk by barriers + VGPR reuse).
//
// Design: one block per (row, 4096-col chunk), 13x1024 blocks. Atomic phase
// additionally sets mask[bin>>2]=1 (4 KB LDS, 1 word per 4-bin group).
// Store phase: each thread reads its 4 mask words (ONE lgkm wait), then
// issues 4 coalesced float4 stores. Common path (mask==0): data is constant
// zero -- no LDS dependency, stores issue back-to-back at full rate. Rare
// path (~40 groups/block): ds_read_b128 + cvt. Every output dword is written
// exactly once -> no same-address hazard -> no vmcnt drain anywhere; global
// stores stay fire-and-forget until endpgm.
// Plain stores, NOT nontemporal (R4: nt bypasses MALL absorption, +10 us).
// 20 KB LDS -> 8 blocks/CU, 32 waves. Raw lgkm-only barriers (2 total).

#define BATCH 1024
#define SEQ 512
#define VOCAB 50257
#define OUT_COLS (VOCAB - 1)   // 50256
#define CHUNK 4096
#define NGROUP (CHUNK / 4)     // 1024 mask groups of 4 bins
#define NBLK_PER_ROW 13        // 12 full chunks + 1104-col tail
#define BLOCK 256

// LDS-only barrier: waits ds ops (lgkmcnt) but does NOT drain global stores
// (__syncthreads would emit s_waitcnt vmcnt(0) and stall the store pipe).
#define LDS_BAR()                                              \
    do {                                                       \
        asm volatile("s_waitcnt lgkmcnt(0)" ::: "memory");     \
        __builtin_amdgcn_s_barrier();                          \
        asm volatile("" ::: "memory");                         \
    } while (0)

__global__ __launch_bounds__(BLOCK) void bow_maskstream_kernel(
    const int* __restrict__ tokens, float* __restrict__ out) {
    __shared__ unsigned int hist[CHUNK];   // 16 KB
    __shared__ unsigned int mask[NGROUP];  // 4 KB

    const int t  = threadIdx.x;
    const int c0 = blockIdx.x * CHUNK;
    const int b  = blockIdx.y;

    // Issue the token load first; its vmcnt wait lands after LDS zeroing +
    // barrier (~300 cyc), hiding most of the load latency.
    const int2 tk = ((const int2*)(tokens + (size_t)b * SEQ))[t];

    // Zero hist (4x uint4/thread) and mask (1x uint4/thread).
    const uint4 z4 = make_uint4(0u, 0u, 0u, 0u);
    #pragma unroll
    for (int k = 0; k < 4; ++k)
        *(uint4*)&hist[t * 4 + k * (BLOCK * 4)] = z4;
    *(uint4*)&mask[t * 4] = z4;

    LDS_BAR();

    // Histogram + mark occupied 4-bin groups. tok==0 dropped via unsigned
    // underflow (tok-1-c0 wraps huge). Mask write races are benign (all 1u).
    unsigned int r;
    r = (unsigned int)(tk.x - 1 - c0);
    if (r < CHUNK) { atomicAdd(&hist[r], 1u); mask[r >> 2] = 1u; }
    r = (unsigned int)(tk.y - 1 - c0);
    if (r < CHUNK) { atomicAdd(&hist[r], 1u); mask[r >> 2] = 1u; }

    LDS_BAR();

    float* orow = out + (size_t)b * OUT_COLS + c0;
    const int ncols = (c0 + CHUNK <= OUT_COLS) ? CHUNK : (OUT_COLS - c0);

    // Batch the 4 mask-word reads (one lgkm wait), then stream stores.
    // Group g = t + 256k covers bins [4g, 4g+4); per-k store addresses are
    // lane-contiguous (1 KB per wave instruction).
    unsigned int m[4];
    #pragma unroll
    for (int k = 0; k < 4; ++k)
        m[k] = mask[t + k * BLOCK];

    #pragma unroll
    for (int k = 0; k < 4; ++k) {
        const int base = t * 4 + k * (BLOCK * 4);  // = 4 * group
        if (base < ncols) {                        // tail chunk: 1104 cols
            if (m[k] == 0u) {
                *(float4*)(orow + base) = make_float4(0.f, 0.f, 0.f, 0.f);
            } else {
                const uint4 h = *(const uint4*)&hist[base];
                *(float4*)(orow + base) = make_float4(
                    (float)h.x, (float)h.y, (float)h.z, (float)h.w);
            }
        }
    }
}

extern "C" void kernel_launch(void* const* d_in, const int* in_sizes, int n_in,
                              void* d_out, int out_size, void* d_ws, size_t ws_size,
                              hipStream_t stream) {
    const int* tokens = (const int*)d_in[0];
    float* out = (float*)d_out;

    bow_maskstream_kernel<<<dim3(NBLK_PER_ROW, BATCH), dim3(BLOCK), 0, stream>>>(
        tokens, out);
}